// Round 3
// baseline (983.615 us; speedup 1.0000x reference)
//
#include <hip/hip_runtime.h>
#include <math.h>

#define Bn   4
#define Sn   1024
#define Dn   1024
#define Hn   16
#define DKn  64
#define MRPn 1000
#define RKU  2049   // Rk rows: u in [0,2048], row 2048 = band over-read pad
#define EP   2112   // E2V padded pitch (u), covers skew-tile over-read

typedef __attribute__((ext_vector_type(8))) short short8;
typedef __attribute__((ext_vector_type(4))) float f32x4;

static __device__ __forceinline__ unsigned short f2bf(float f) {
    unsigned u = __float_as_uint(f);
    u += 0x7FFF + ((u >> 16) & 1);          // RNE
    return (unsigned short)(u >> 16);
}
static __device__ __forceinline__ float bf2f(unsigned short h) {
    return __uint_as_float((unsigned)h << 16);
}

// ---------------------------------------------------------------------------
// fp32 -> bf16 cast, 4 elems/thread.
// ---------------------------------------------------------------------------
__global__ __launch_bounds__(256) void cast_f32_bf16(
    const float* __restrict__ s, unsigned short* __restrict__ d, int n)
{
    int i = (blockIdx.x * 256 + threadIdx.x) * 4;
    if (i >= n) return;
    float4 v = *(const float4*)(s + i);
    ushort4 o;
    o.x = f2bf(v.x); o.y = f2bf(v.y); o.z = f2bf(v.z); o.w = f2bf(v.w);
    *(ushort4*)(d + i) = o;
}

// ---------------------------------------------------------------------------
// C = A[M,K](bf16) @ W[N,K](bf16)^T + bias[N].
// mode 0: fp32 out C[M,N].
// mode 1: split bf16 out, head layout Chi/Clo[((b*16+h)*1024+q)*64+d].
// mode 2: bf16 transposed head layout Chi[((b*16+h)*64+d)*1024+tok] (V^T).
// ---------------------------------------------------------------------------
#define LP 40   // LDS row pitch in bf16 elems
__global__ __launch_bounds__(256) void gemm_bf16_mfma(
    const unsigned short* __restrict__ A, const unsigned short* __restrict__ W,
    const float* __restrict__ bias, float* __restrict__ C,
    unsigned short* __restrict__ Chi, unsigned short* __restrict__ Clo,
    int M, int N, int K, int mode)
{
    __shared__ unsigned short As[128 * LP];
    __shared__ unsigned short Bs[128 * LP];
    const int tid  = threadIdx.x;
    const int lane = tid & 63;
    const int wave = tid >> 6;
    const int m0 = blockIdx.y * 128, n0 = blockIdx.x * 128;
    const int wm = (wave & 1) * 64, wn = (wave >> 1) * 64;
    const int fr   = lane & 15;
    const int quad = lane >> 4;

    f32x4 acc[4][4];
#pragma unroll
    for (int i = 0; i < 4; ++i)
#pragma unroll
        for (int j = 0; j < 4; ++j) acc[i][j] = (f32x4){0.f, 0.f, 0.f, 0.f};

    const int srow   = tid >> 2;
    const int schunk = (tid & 3) * 8;

    for (int kb = 0; kb < K; kb += 32) {
        const unsigned short* ga = A + (size_t)(m0 + srow) * K + kb + schunk;
        const unsigned short* gb = W + (size_t)(n0 + srow) * K + kb + schunk;
        short8 a0 = *(const short8*)ga;
        short8 a1 = *(const short8*)(ga + (size_t)64 * K);
        short8 b0 = *(const short8*)gb;
        short8 b1 = *(const short8*)(gb + (size_t)64 * K);
        __syncthreads();
        *(short8*)&As[srow * LP + schunk]        = a0;
        *(short8*)&As[(srow + 64) * LP + schunk] = a1;
        *(short8*)&Bs[srow * LP + schunk]        = b0;
        *(short8*)&Bs[(srow + 64) * LP + schunk] = b1;
        __syncthreads();

        short8 af[4], bf[4];
#pragma unroll
        for (int mi = 0; mi < 4; ++mi)
            af[mi] = *(const short8*)&As[(wm + 16 * mi + fr) * LP + quad * 8];
#pragma unroll
        for (int ni = 0; ni < 4; ++ni)
            bf[ni] = *(const short8*)&Bs[(wn + 16 * ni + fr) * LP + quad * 8];
#pragma unroll
        for (int mi = 0; mi < 4; ++mi)
#pragma unroll
            for (int ni = 0; ni < 4; ++ni)
                acc[mi][ni] = __builtin_amdgcn_mfma_f32_16x16x32_bf16(
                    af[mi], bf[ni], acc[mi][ni], 0, 0, 0);
    }

    if (mode == 0) {
#pragma unroll
        for (int ni = 0; ni < 4; ++ni) {
            int cc = n0 + wn + 16 * ni + fr;
            float bv = bias[cc];
#pragma unroll
            for (int mi = 0; mi < 4; ++mi) {
                int rbase = m0 + wm + 16 * mi + quad * 4;
#pragma unroll
                for (int r = 0; r < 4; ++r)
                    C[(size_t)(rbase + r) * N + cc] = acc[mi][ni][r] + bv;
            }
        }
    } else if (mode == 1) {
#pragma unroll
        for (int ni = 0; ni < 4; ++ni) {
            int cc = n0 + wn + 16 * ni + fr;
            int h = cc >> 6, d = cc & 63;
            float bv = bias[cc];
#pragma unroll
            for (int mi = 0; mi < 4; ++mi) {
                int rbase = m0 + wm + 16 * mi + quad * 4;
                int b = rbase >> 10, q0 = rbase & 1023;
#pragma unroll
                for (int r = 0; r < 4; ++r) {
                    float val = acc[mi][ni][r] + bv;
                    unsigned short hi = f2bf(val);
                    unsigned short lo = f2bf(val - bf2f(hi));
                    size_t o = (((size_t)b * Hn + h) * Sn + q0 + r) * DKn + d;
                    Chi[o] = hi; Clo[o] = lo;
                }
            }
        }
    } else {  // mode 2: V^T bf16
#pragma unroll
        for (int ni = 0; ni < 4; ++ni) {
            int cc = n0 + wn + 16 * ni + fr;
            int h = cc >> 6, d = cc & 63;
            float bv = bias[cc];
#pragma unroll
            for (int mi = 0; mi < 4; ++mi) {
                int rbase = m0 + wm + 16 * mi + quad * 4;
                int b = rbase >> 10, tok0 = rbase & 1023;
                ushort4 o4;
#pragma unroll
                for (int r = 0; r < 4; ++r) o4[r] = f2bf(acc[mi][ni][r] + bv);
                *(ushort4*)&Chi[(((size_t)b * Hn + h) * DKn + d) * Sn + tok0] = o4;
            }
        }
    }
}

// ---------------------------------------------------------------------------
// Rk[u][d] hi/lo split-bf16 of embK[clip(u-1024)+MRP][d], u in [0,RKU)
// ---------------------------------------------------------------------------
__global__ __launch_bounds__(256) void build_rk(
    const float* __restrict__ embK, unsigned short* __restrict__ Rh,
    unsigned short* __restrict__ Rl)
{
    int i = (blockIdx.x * 256 + threadIdx.x) * 4;
    if (i >= RKU * DKn) return;
    int u = i >> 6, d0 = i & 63;
    int t = min(max(u - 1024, -MRPn), MRPn);
    float4 v = *(const float4*)&embK[(size_t)(t + MRPn) * DKn + d0];
    ushort4 hi, lo;
    hi.x = f2bf(v.x); lo.x = f2bf(v.x - bf2f(hi.x));
    hi.y = f2bf(v.y); lo.y = f2bf(v.y - bf2f(hi.y));
    hi.z = f2bf(v.z); lo.z = f2bf(v.z - bf2f(hi.z));
    hi.w = f2bf(v.w); lo.w = f2bf(v.w - bf2f(hi.w));
    *(ushort4*)&Rh[i] = hi;
    *(ushort4*)&Rl[i] = lo;
}

// ---------------------------------------------------------------------------
// E2V[d][u] = bf16(embV[clip(u-1024)+MRP][d]), d-major, pitch EP
// ---------------------------------------------------------------------------
__global__ __launch_bounds__(256) void build_e2v(
    const float* __restrict__ embV, unsigned short* __restrict__ E2V)
{
    int i = (blockIdx.x * 256 + threadIdx.x) * 8;
    if (i >= DKn * EP) return;
    int d = i / EP, u0 = i % EP;
    short8 o;
#pragma unroll
    for (int e = 0; e < 8; ++e) {
        int t = u0 + e - 1024;
        t = min(max(t, -MRPn), MRPn);
        o[e] = (short)f2bf(embV[(size_t)(t + MRPn) * DKn + d]);
    }
    *(short8*)&E2V[i] = o;
}

// ---------------------------------------------------------------------------
// Fused logits + softmax + AV. One block = (bh, 32-q strip), 4 waves.
// Phase 1 (16 k-tiles of 64): 3-term-split MFMA QK^T + sheared Q.Rk^T band,
//   per-tile row max m_t, P_t = exp(x - m_t) stored bf16 in LDS, online (m,s).
// Phase 2: rescale P by exp(m_t - m_fin)/s, write fp32 weights (coalesced),
//   write bf16 weights back to LDS; AV = P@V^T (LDS A-frags) + skew P@E2V^T
//   (LDS->LDS staged band gather). X written bf16 for the Wo GEMM.
// LDS = 79.5 KB -> 2 blocks/CU.
// ---------------------------------------------------------------------------
__global__ __launch_bounds__(256) void attn_fused(
    const unsigned short* __restrict__ Qh, const unsigned short* __restrict__ Ql,
    const unsigned short* __restrict__ Kh, const unsigned short* __restrict__ Kl,
    const unsigned short* __restrict__ Rh, const unsigned short* __restrict__ Rl,
    const unsigned short* __restrict__ Vt, const unsigned short* __restrict__ E2V,
    float* __restrict__ Lw, unsigned short* __restrict__ Xbf)
{
    __shared__ unsigned short Pbuf[32][1032];          // 66048 B
    __shared__ __align__(16) char scratch[12800];      // RelU | ftab+Ssk
    __shared__ float rowred[32][2];
    __shared__ float mrun[32], srun[32];
    __shared__ float mts[16][32];

    float (*RelU)[100] = (float(*)[100])scratch;                    // phase 1
    float (*ftab)[32]  = (float(*)[32])scratch;                     // phase 2
    unsigned short (*Ssk)[72] = (unsigned short(*)[72])(scratch + 2048);

    const int tid = threadIdx.x;
    const int lane = tid & 63, wave = tid >> 6;
    const int wy = wave >> 1, wx = wave & 1;
    const int fr = lane & 15, quad = lane >> 4;
    const int n = blockIdx.x;
    const int virt = (n & 7) * 256 + (n >> 3);    // 8 bh per XCD
    const int bh = virt >> 5, q0 = (virt & 31) * 32;

    if (tid < 32) { mrun[tid] = -INFINITY; srun[tid] = 0.f; }

    // Q fragments (fixed per block)
    const unsigned short* qbh = Qh + ((size_t)bh * Sn + q0 + wy * 16 + fr) * DKn;
    const unsigned short* qbl = Ql + ((size_t)bh * Sn + q0 + wy * 16 + fr) * DKn;
    short8 aH[2], aL[2];
#pragma unroll
    for (int kbi = 0; kbi < 2; ++kbi) {
        aH[kbi] = *(const short8*)(qbh + kbi * 32 + quad * 8);
        aL[kbi] = *(const short8*)(qbl + kbi * 32 + quad * 8);
    }

    // ================= phase 1 =================
    for (int kt = 0; kt < 16; ++kt) {
        const int k0 = kt * 64;
        const unsigned short* kbh = Kh + ((size_t)bh * Sn + k0 + wx * 32 + fr) * DKn;
        const unsigned short* kbl = Kl + ((size_t)bh * Sn + k0 + wx * 32 + fr) * DKn;
        const int ubase = k0 - q0 + 993;                  // abs u of band col 0
        const unsigned short* rbh = Rh + ((size_t)(ubase + wx * 48) + fr) * DKn;
        const unsigned short* rbl = Rl + ((size_t)(ubase + wx * 48) + fr) * DKn;

        f32x4 acc2[2], rel3[3];
#pragma unroll
        for (int i = 0; i < 2; ++i) acc2[i] = (f32x4){0.f, 0.f, 0.f, 0.f};
#pragma unroll
        for (int i = 0; i < 3; ++i) rel3[i] = (f32x4){0.f, 0.f, 0.f, 0.f};

#pragma unroll
        for (int kbi = 0; kbi < 2; ++kbi) {
            short8 bKH[2], bKL[2], bRH[3], bRL[3];
#pragma unroll
            for (int ni = 0; ni < 2; ++ni) {
                size_t off = (size_t)16 * ni * DKn + kbi * 32 + quad * 8;
                bKH[ni] = *(const short8*)(kbh + off);
                bKL[ni] = *(const short8*)(kbl + off);
            }
#pragma unroll
            for (int ni = 0; ni < 3; ++ni) {
                size_t off = (size_t)16 * ni * DKn + kbi * 32 + quad * 8;
                bRH[ni] = *(const short8*)(rbh + off);
                bRL[ni] = *(const short8*)(rbl + off);
            }
#pragma unroll
            for (int ni = 0; ni < 2; ++ni) {
                acc2[ni] = __builtin_amdgcn_mfma_f32_16x16x32_bf16(
                    aH[kbi], bKH[ni], acc2[ni], 0, 0, 0);
                acc2[ni] = __builtin_amdgcn_mfma_f32_16x16x32_bf16(
                    aL[kbi], bKH[ni], acc2[ni], 0, 0, 0);
                acc2[ni] = __builtin_amdgcn_mfma_f32_16x16x32_bf16(
                    aH[kbi], bKL[ni], acc2[ni], 0, 0, 0);
            }
#pragma unroll
            for (int ni = 0; ni < 3; ++ni) {
                rel3[ni] = __builtin_amdgcn_mfma_f32_16x16x32_bf16(
                    aH[kbi], bRH[ni], rel3[ni], 0, 0, 0);
                rel3[ni] = __builtin_amdgcn_mfma_f32_16x16x32_bf16(
                    aL[kbi], bRH[ni], rel3[ni], 0, 0, 0);
                rel3[ni] = __builtin_amdgcn_mfma_f32_16x16x32_bf16(
                    aH[kbi], bRL[ni], rel3[ni], 0, 0, 0);
            }
        }

        // shear rel band through LDS
#pragma unroll
        for (int ni = 0; ni < 3; ++ni)
#pragma unroll
            for (int r = 0; r < 4; ++r)
                RelU[wy * 16 + quad * 4 + r][wx * 48 + 16 * ni + fr] = rel3[ni][r];
        __syncthreads();

        float lg[2][4], mt4[4];
#pragma unroll
        for (int ni = 0; ni < 2; ++ni)
#pragma unroll
            for (int r = 0; r < 4; ++r) {
                int row = wy * 16 + quad * 4 + r;
                int c = wx * 32 + 16 * ni + fr;
                lg[ni][r] = acc2[ni][r] + RelU[row][c - row + 31];
            }

        // tile row max
#pragma unroll
        for (int r = 0; r < 4; ++r) {
            float m = fmaxf(lg[0][r], lg[1][r]);
#pragma unroll
            for (int o = 1; o < 16; o <<= 1) m = fmaxf(m, __shfl_xor(m, o, 16));
            if (fr == 0) rowred[wy * 16 + quad * 4 + r][wx] = m;
        }
        __syncthreads();
#pragma unroll
        for (int r = 0; r < 4; ++r)
            mt4[r] = fmaxf(rowred[wy * 16 + quad * 4 + r][0],
                           rowred[wy * 16 + quad * 4 + r][1]);

        // exp, store P, row sums
        float s4[4];
#pragma unroll
        for (int r = 0; r < 4; ++r) s4[r] = 0.f;
#pragma unroll
        for (int ni = 0; ni < 2; ++ni)
#pragma unroll
            for (int r = 0; r < 4; ++r) {
                float p = expf(lg[ni][r] - mt4[r]);
                Pbuf[wy * 16 + quad * 4 + r][k0 + wx * 32 + 16 * ni + fr] = f2bf(p);
                s4[r] += p;
            }
#pragma unroll
        for (int r = 0; r < 4; ++r)
#pragma unroll
            for (int o = 1; o < 16; o <<= 1) s4[r] += __shfl_xor(s4[r], o, 16);
        __syncthreads();     // mt4 reads done before rowred reuse
        if (fr == 0)
#pragma unroll
            for (int r = 0; r < 4; ++r)
                rowred[wy * 16 + quad * 4 + r][wx] = s4[r];
        __syncthreads();
        if (wx == 0 && fr == 0) {
#pragma unroll
            for (int r = 0; r < 4; ++r) {
                int row = wy * 16 + quad * 4 + r;
                float st = rowred[row][0] + rowred[row][1];
                float mo = mrun[row], mtv = mt4[r];
                float mn = fmaxf(mo, mtv);
                srun[row] = srun[row] * expf(mo - mn) + st * expf(mtv - mn);
                mrun[row] = mn;
                mts[kt][row] = mtv;
            }
        }
        __syncthreads();
    }

    // ================= phase 2 =================
    // ftab[kt][row] = exp(m_t - m_fin) / s_fin
    for (int i = tid; i < 512; i += 256) {
        int ktt = i >> 5, row = i & 31;
        ftab[ktt][row] = expf(mts[ktt][row] - mrun[row]) / srun[row];
    }
    __syncthreads();

    // rescale + coalesced fp32 weights write + bf16 writeback
    float* Lrow = Lw + ((size_t)bh * Sn + q0) * Sn;
#pragma unroll
    for (int rr = 0; rr < 8; ++rr) {
        int row = wave * 8 + rr;
#pragma unroll
        for (int c4 = 0; c4 < 4; ++c4) {
            int col = c4 * 256 + lane * 4;
            ushort4 pv = *(const ushort4*)&Pbuf[row][col];
            float f = ftab[col >> 6][row];
            float4 w;
            w.x = bf2f(pv.x) * f; w.y = bf2f(pv.y) * f;
            w.z = bf2f(pv.z) * f; w.w = bf2f(pv.w) * f;
            *(float4*)&Lrow[(size_t)row * Sn + col] = w;
            ushort4 o;
            o.x = f2bf(w.x); o.y = f2bf(w.y); o.z = f2bf(w.z); o.w = f2bf(w.w);
            *(ushort4*)&Pbuf[row][col] = o;
        }
    }
    __syncthreads();

    // AV plain: X[q][d] += sum_k W[q,k] V[k,d]
    f32x4 av[2];
    av[0] = (f32x4){0.f, 0.f, 0.f, 0.f};
    av[1] = (f32x4){0.f, 0.f, 0.f, 0.f};
    const unsigned short* vb = Vt + ((size_t)bh * DKn + wx * 32 + fr) * Sn;
    for (int kb = 0; kb < Sn; kb += 32) {
        short8 a  = *(const short8*)&Pbuf[wy * 16 + fr][kb + quad * 8];
        short8 b0 = *(const short8*)(vb + kb + quad * 8);
        short8 b1 = *(const short8*)(vb + (size_t)16 * Sn + kb + quad * 8);
        av[0] = __builtin_amdgcn_mfma_f32_16x16x32_bf16(a, b0, av[0], 0, 0, 0);
        av[1] = __builtin_amdgcn_mfma_f32_16x16x32_bf16(a, b1, av[1], 0, 0, 0);
    }

    // AV skew: X[q][d] += sum_u W[q, q+u-1024] E2V[d][u]
    const int ub0 = 992 - q0;                     // mult of 32, band start
    const unsigned short* eb = E2V + (size_t)(wx * 32 + fr) * EP;
    for (int t = 0; t < 17; ++t) {
        const int ub = ub0 + t * 64;
        __syncthreads();                          // prior Ssk reads done
        {
            int row = tid >> 3, uc = (tid & 7) * 8;
            short8 v;
#pragma unroll
            for (int e = 0; e < 8; ++e) {
                int u = ub + uc + e;
                int k = q0 + row + u - 1024;
                v[e] = ((unsigned)k < 1024u) ? (short)Pbuf[row][k] : (short)0;
            }
            *(short8*)&Ssk[row][uc] = v;
        }
        __syncthreads();
#pragma unroll
        for (int uc2 = 0; uc2 < 2; ++uc2) {
            short8 a  = *(const short8*)&Ssk[wy * 16 + fr][uc2 * 32 + quad * 8];
            short8 b0 = *(const short8*)(eb + ub + uc2 * 32 + quad * 8);
            short8 b1 = *(const short8*)(eb + (size_t)16 * EP + ub + uc2 * 32 + quad * 8);
            av[0] = __builtin_amdgcn_mfma_f32_16x16x32_bf16(a, b0, av[0], 0, 0, 0);
            av[1] = __builtin_amdgcn_mfma_f32_16x16x32_bf16(a, b1, av[1], 0, 0, 0);
        }
    }

    // epilogue: X bf16 for Wo GEMM
    const int b = bh >> 4, h = bh & 15;
#pragma unroll
    for (int ni = 0; ni < 2; ++ni) {
        int d = wx * 32 + 16 * ni + fr;
#pragma unroll
        for (int r = 0; r < 4; ++r) {
            int q = q0 + wy * 16 + quad * 4 + r;
            Xbf[((size_t)(b * Sn + q)) * Dn + h * DKn + d] = f2bf(av[ni][r]);
        }
    }
}

// ---------------------------------------------------------------------------
extern "C" void kernel_launch(void* const* d_in, const int* in_sizes, int n_in,
                              void* d_out, int out_size, void* d_ws, size_t ws_size,
                              hipStream_t stream)
{
    const float* query = (const float*)d_in[0];
    const float* key   = (const float*)d_in[1];
    const float* value = (const float*)d_in[2];
    const float* Wq    = (const float*)d_in[3];
    const float* bq    = (const float*)d_in[4];
    const float* Wk    = (const float*)d_in[5];
    const float* bk    = (const float*)d_in[6];
    const float* Wv    = (const float*)d_in[7];
    const float* bv    = (const float*)d_in[8];
    const float* Wo    = (const float*)d_in[9];
    const float* bo    = (const float*)d_in[10];
    const float* embK  = (const float*)d_in[11];
    const float* embV  = (const float*)d_in[12];

    const size_t NTOK = (size_t)Bn * Sn;          // 4096
    const size_t PROJ = NTOK * Dn;                // 4,194,304
    const size_t WSZ  = (size_t)Dn * Dn;          // 1,048,576

    unsigned short* u16 = (unsigned short*)d_ws;
    unsigned short* Abf = u16;                    // bf16 [4096,1024] (reused)
    unsigned short* Wqb = Abf + PROJ;
    unsigned short* Wkb = Wqb + WSZ;
    unsigned short* Wvb = Wkb + WSZ;
    unsigned short* Wob = Wvb + WSZ;
    unsigned short* Qhi = Wob + WSZ;              // [64bh][1024q][64d]
    unsigned short* Qlo = Qhi + PROJ;
    unsigned short* Khi = Qlo + PROJ;
    unsigned short* Klo = Khi + PROJ;
    unsigned short* Vtb = Klo + PROJ;             // [64bh][64d][1024k]
    unsigned short* E2V = Vtb + PROJ;             // [64d][EP]
    unsigned short* RkH = E2V + (size_t)DKn * EP; // [RKU][64]
    unsigned short* RkL = RkH + (size_t)RKU * DKn;

    float* outp = (float*)d_out;                  // [B,S,D]
    float* Wt   = outp + PROJ;                    // weights [B,H,S,S]

    const int CAST_W_GRID = (int)(WSZ / 4 / 256);
    const int CAST_A_GRID = (int)(PROJ / 4 / 256);
    dim3 gemmGrid(Dn / 128, (int)(NTOK / 128));   // (8, 32)

    build_e2v<<<(DKn * EP / 8 + 255) / 256, 256, 0, stream>>>(embV, E2V);
    build_rk<<<(RKU * DKn / 4 + 255) / 256, 256, 0, stream>>>(embK, RkH, RkL);

    cast_f32_bf16<<<CAST_W_GRID, 256, 0, stream>>>(Wq, Wqb, (int)WSZ);
    cast_f32_bf16<<<CAST_W_GRID, 256, 0, stream>>>(Wk, Wkb, (int)WSZ);
    cast_f32_bf16<<<CAST_W_GRID, 256, 0, stream>>>(Wv, Wvb, (int)WSZ);
    cast_f32_bf16<<<CAST_W_GRID, 256, 0, stream>>>(Wo, Wob, (int)WSZ);

    cast_f32_bf16<<<CAST_A_GRID, 256, 0, stream>>>(query, Abf, (int)PROJ);
    gemm_bf16_mfma<<<gemmGrid, 256, 0, stream>>>(Abf, Wqb, bq, nullptr, Qhi, Qlo,
                                                 (int)NTOK, Dn, Dn, 1);
    cast_f32_bf16<<<CAST_A_GRID, 256, 0, stream>>>(key, Abf, (int)PROJ);
    gemm_bf16_mfma<<<gemmGrid, 256, 0, stream>>>(Abf, Wkb, bk, nullptr, Khi, Klo,
                                                 (int)NTOK, Dn, Dn, 1);
    cast_f32_bf16<<<CAST_A_GRID, 256, 0, stream>>>(value, Abf, (int)PROJ);
    gemm_bf16_mfma<<<gemmGrid, 256, 0, stream>>>(Abf, Wvb, bv, nullptr, Vtb, nullptr,
                                                 (int)NTOK, Dn, Dn, 2);

    attn_fused<<<Bn * Hn * (Sn / 32), 256, 0, stream>>>(
        Qhi, Qlo, Khi, Klo, RkH, RkL, Vtb, E2V, Wt, Abf);

    gemm_bf16_mfma<<<gemmGrid, 256, 0, stream>>>(Abf, Wob, bo, outp, nullptr, nullptr,
                                                 (int)NTOK, Dn, Dn, 0);
}